// Round 17
// baseline (116.413 us; speedup 1.0000x reference)
//
#include <hip/hip_runtime.h>
#include <hip/hip_bf16.h>

typedef __attribute__((ext_vector_type(4))) float f32x4;
typedef __attribute__((ext_vector_type(8))) short bh8;

#define DEVI static __device__ __forceinline__

constexpr int Bn = 2, T = 2048, C = 1024, H = 16, HD = 64;
constexpr int BH = Bn * H;   // 32
constexpr int M  = Bn * T;   // 4096
// fold 1/sqrt(HD) and log2(e) into Q so softmax uses exp2
constexpr float QSC = 0.125f * 1.44269504088896f;

DEVI unsigned short f2bf(float f) {
  unsigned int u = __builtin_bit_cast(unsigned int, f);
  u += 0x7FFFu + ((u >> 16) & 1u);   // RTNE
  return (unsigned short)(u >> 16);
}

DEVI unsigned int cvtpk(float lo, float hi) {  // 2xf32 -> packed 2xbf16 (1 VALU op)
  unsigned int r;
  asm("v_cvt_pk_bf16_f32 %0, %1, %2" : "=v"(r) : "v"(lo), "v"(hi));
  return r;
}

DEVI float fexp2(float x) {  // raw v_exp_f32 (2^x); CDNA has HW interlocks
  float r;
  asm("v_exp_f32 %0, %1" : "=v"(r) : "v"(x));
  return r;
}

DEVI void gload16(const void* g, void* l) {
  __builtin_amdgcn_global_load_lds((const __attribute__((address_space(1))) void*)g,
                                   (__attribute__((address_space(3))) void*)l,
                                   16, 0, 0);
}

// one fused fp32->bf16 convert for x | w_attn | w_proj (outputs contiguous in ws)
__global__ __launch_bounds__(256) void cvt_all(const float* __restrict__ x,
                                               const float* __restrict__ wa,
                                               const float* __restrict__ wp,
                                               unsigned short* __restrict__ out) {
  constexpr size_t n0 = (size_t)M * C;            // x
  constexpr size_t n1 = n0 + (size_t)3 * C * C;   // + w_attn
  const size_t i = ((size_t)blockIdx.x * 256 + threadIdx.x) * 4;
  const float* src;
  size_t off;
  if (i < n0)      { src = x;  off = i; }
  else if (i < n1) { src = wa; off = i - n0; }
  else             { src = wp; off = i - n1; }
  const float4 v = *(const float4*)(src + off);
  ushort4 o;
  o.x = f2bf(v.x); o.y = f2bf(v.y); o.z = f2bf(v.z); o.w = f2bf(v.w);
  *(ushort4*)(out + i) = o;
}

// C = A @ B^T (+bias). 128x128 tile, BK=64, 4 waves, 16x16x32 bf16 MFMA.
// R5-proven SINGLE-BUFFERED structure, DEFAULT block mapping (frozen:
// dbuf/8-phase/XCD-swizzle all regressed on this problem shape).
// EPI 0: fp32 out + bias. EPI 1: qkv scatter; V kv-PERMUTED (see attn).
template <int EPI>
__global__ __launch_bounds__(256) void gemm_bt(
    const unsigned short* __restrict__ A, const unsigned short* __restrict__ Bw,
    const float* __restrict__ bias, int N, int K,
    unsigned short* __restrict__ Qb, unsigned short* __restrict__ Kb,
    unsigned short* __restrict__ Vb, float* __restrict__ Outf) {
  __shared__ unsigned short As[128 * 64];
  __shared__ unsigned short Bs[128 * 64];

  const int tid  = threadIdx.x;
  const int lane = tid & 63;
  const int wid  = tid >> 6;
  const int wm = wid >> 1, wn = wid & 1;
  const int m0 = blockIdx.y * 128;
  const int n0 = blockIdx.x * 128;

  const int srow = lane >> 3;
  const int gp   = lane & 7;

  const unsigned short* Ab = A + (size_t)m0 * K;
  const unsigned short* Bb = Bw + (size_t)n0 * K;

  f32x4 acc[4][4] = {};

  for (int kt = 0; kt < K; kt += 64) {
    __syncthreads();
#pragma unroll
    for (int j = 0; j < 4; ++j) {
      const int row = wid * 32 + j * 8 + srow;
      const int gs  = gp ^ (row & 7);
      gload16(Ab + (size_t)row * K + kt + gs * 8, &As[(wid * 32 + j * 8) * 64]);
    }
#pragma unroll
    for (int j = 0; j < 4; ++j) {
      const int row = wid * 32 + j * 8 + srow;
      const int gs  = gp ^ (row & 7);
      gload16(Bb + (size_t)row * K + kt + gs * 8, &Bs[(wid * 32 + j * 8) * 64]);
    }
    __syncthreads();

#pragma unroll
    for (int kk = 0; kk < 2; ++kk) {
      bh8 af[4], bfr[4];
#pragma unroll
      for (int i = 0; i < 4; ++i) {
        const int row  = wm * 64 + i * 16 + (lane & 15);
        const int gran = kk * 4 + (lane >> 4);
        af[i] = *(const bh8*)&As[row * 64 + ((gran ^ (row & 7)) * 8)];
      }
#pragma unroll
      for (int j = 0; j < 4; ++j) {
        const int row  = wn * 64 + j * 16 + (lane & 15);
        const int gran = kk * 4 + (lane >> 4);
        bfr[j] = *(const bh8*)&Bs[row * 64 + ((gran ^ (row & 7)) * 8)];
      }
#pragma unroll
      for (int i = 0; i < 4; ++i)
#pragma unroll
        for (int j = 0; j < 4; ++j)
          acc[i][j] = __builtin_amdgcn_mfma_f32_16x16x32_bf16(af[i], bfr[j],
                                                              acc[i][j], 0, 0, 0);
    }
  }

  const int rbase = m0 + wm * 64 + ((lane >> 4) << 2);
  const int cbase = n0 + wn * 64 + (lane & 15);

  if (EPI == 0) {
#pragma unroll
    for (int j = 0; j < 4; ++j) {
      const int n = cbase + j * 16;
      const float bv = bias[n];
#pragma unroll
      for (int i = 0; i < 4; ++i)
#pragma unroll
        for (int r = 0; r < 4; ++r) {
          const int m = rbase + i * 16 + r;
          Outf[(size_t)m * N + n] = acc[i][j][r] + bv;
        }
    }
  } else {
#pragma unroll
    for (int j = 0; j < 4; ++j) {
      const int n = cbase + j * 16;
      const float bv = bias[n];
      const int part = n >> 10;      // 0:q 1:k 2:v
      const int nn = n & 1023;
      const int h = nn >> 6, d = nn & 63;
#pragma unroll
      for (int i = 0; i < 4; ++i)
#pragma unroll
        for (int r = 0; r < 4; ++r) {
          const int m = rbase + i * 16 + r;
          const int b = m >> 11, t = m & (T - 1);
          const int bh = b * H + h;
          const float val = acc[i][j][r] + bv;
          if (part == 0)
            Qb[((size_t)(bh * T + t)) * HD + d] = f2bf(val * QSC);
          else if (part == 1)
            Kb[((size_t)(bh * T + t)) * HD + d] = f2bf(val);
          else {
            // kv-permutation (bits 0..4 only -> valid for any KVBLK>=32):
            // kp=[..|b1|l4|r] -> kap=[..|l4|b1|r]
            const int kp  = t & 127;
            const int kap = (kp & ~31) | (((kp >> 2) & 3) << 3) |
                            (((kp >> 4) & 1) << 2) | (kp & 3);
            const int tp  = (t & ~127) | kap;
            Vb[((size_t)(bh * HD + d)) * T + tp] = f2bf(val);  // transposed+permuted
          }
        }
    }
  }
}

// ---------------------------------------------------------------------------
// Flash attention, causal. Grid: (BH=32, 16). Block: 512 thr = 8 waves.
// R17: UNPAIRED q-tiles -> 512 blocks -> 2 blocks/CU = 16 waves/CU (R13 was
// grid-limited to 1 block/CU = 8 waves/CU). Block structure is R13's proven
// one: kv-parity groups g=waves[4g,4g+4), KVBLK=64, 32 q/wave (fragment
// sharing), own dbuf K/V LDS + own online-softmax state; per-group units
// nU=qa+1 (equal for both groups -> lockstep). Single pass (no mid-loop
// flush); merge scratch ALIASED onto the dead K/V LDS after the loop ->
// LDS = 64KB exactly -> 2 blocks/CU. y-map qa = y<8 ? y : 23-y pairs linear
// ids c,c+256 as (qa,15-qa) of the SAME bh: balanced per-CU work (17 units)
// + shared K/V in L2 under round-robin dispatch (perf heuristic only).
// Swapped QK^T, in-register P via cvtpk (V kv-permuted at GEMM1), defer-max.
// ---------------------------------------------------------------------------
__global__ __launch_bounds__(512, 4) void attn(
    const unsigned short* __restrict__ Qb, const unsigned short* __restrict__ Kb,
    const unsigned short* __restrict__ Vb, unsigned short* __restrict__ Yb) {
  // [kv][group][dbuf]: K = SMEM[0][g][b], V = SMEM[1][g][b]; 64KB total.
  // After the loop the whole region is dead -> reused as fp32 merge scratch.
  __shared__ unsigned short SMEM[2][2][2][64 * 64];

  const int tid  = threadIdx.x;
  const int lane = tid & 63;
  const int wid  = tid >> 6;          // 0..7
  const int g    = wid >> 2;          // kv-parity group
  const int wv   = wid & 3;           // wave within group
  const int bh   = blockIdx.x;
  const int b = bh >> 4, h = bh & 15;
  const int y  = blockIdx.y;          // 0..15
  const int qa = (y < 8) ? y : 23 - y;  // pairing map: ids c,c+256 -> (qa,15-qa)
  const int nU = qa + 1;              // kv units (KVBLK=64) per group

  const int l4  = lane >> 4;          // 0..3
  const int l15 = lane & 15;

  const unsigned short* Kbh = Kb + (size_t)bh * T * HD;
  const unsigned short* Vbh = Vb + (size_t)bh * HD * T;

  const int sr = lane >> 3, sg = lane & 7;

  // Q fragments (B-operand), 2 chunks x 2 kk (identical for both groups)
  bh8 qk[2][2];
#pragma unroll
  for (int c = 0; c < 2; ++c) {
    const size_t qo =
        ((size_t)(bh * T + qa * 128 + wv * 32 + c * 16 + l15)) * HD + l4 * 8;
    qk[c][0] = *(const bh8*)&Qb[qo];
    qk[c][1] = *(const bh8*)&Qb[qo + 32];
  }

  f32x4 o[2][4] = {};
  float mcur[2] = {-1e30f, -1e30f}, lsum[2] = {0.f, 0.f};

  auto stage = [&](int buf, int kt) {
#pragma unroll
    for (int sl = 0; sl < 2; ++sl) {
      const int row = wv * 16 + sl * 8 + sr;
      const int gs  = sg ^ (row & 7);
      gload16(Kbh + (size_t)(kt + row) * HD + gs * 8,
              &SMEM[0][g][buf][(wv * 16 + sl * 8) * 64]);
      gload16(Vbh + (size_t)row * T + kt + gs * 8,
              &SMEM[1][g][buf][(wv * 16 + sl * 8) * 64]);
    }
  };

  // prologue: stage this group's unit 0 (kv parity g) into buffer 0
  stage(0, g * 64);
  __syncthreads();

  int cur = 0;
  for (int j = 0; j < nU; ++j) {
    // ---- prefetch this group's next unit ----
    if (j + 1 < nU) stage(cur ^ 1, (2 * (j + 1) + g) * 64);

    const int kt = (2 * j + g) * 64;   // absolute kv offset of this unit

    // ---- S^T = K Q^T : s[c][jj][r] = S[kv=kt+jj*16+l4*4+r][q=..+c*16+l15] --
    f32x4 s[2][4] = {};
#pragma unroll
    for (int kk = 0; kk < 2; ++kk) {
      __builtin_amdgcn_s_setprio(1);
#pragma unroll
      for (int jj = 0; jj < 4; ++jj) {
        const int row  = jj * 16 + l15;
        const int gran = kk * 4 + l4;
        const bh8 kfr =
            *(const bh8*)&SMEM[0][g][cur][row * 64 + ((gran ^ (row & 7)) * 8)];
        s[0][jj] = __builtin_amdgcn_mfma_f32_16x16x32_bf16(kfr, qk[0][kk], s[0][jj], 0, 0, 0);
        s[1][jj] = __builtin_amdgcn_mfma_f32_16x16x32_bf16(kfr, qk[1][kk], s[1][jj], 0, 0, 0);
      }
      __builtin_amdgcn_s_setprio(0);
    }

    // ---- causal mask (diag-touching units only: the last unit per group) --
    if (kt >= qa * 128) {
      const int kbase = kt - qa * 128;
#pragma unroll
      for (int c = 0; c < 2; ++c) {
        const int qloc = wv * 32 + c * 16 + l15;
#pragma unroll
        for (int jj = 0; jj < 4; ++jj)
#pragma unroll
          for (int r = 0; r < 4; ++r) {
            const int kvl = kbase + jj * 16 + l4 * 4 + r;
            if (kvl > qloc) s[c][jj][r] = -1e30f;
          }
      }
    }

    // ---- online softmax: per-lane rows (one per chunk), 2 shuffles each ----
    float mx[2];
#pragma unroll
    for (int c = 0; c < 2; ++c) {
      float m = fmaxf(fmaxf(s[c][0][0], s[c][0][1]), fmaxf(s[c][0][2], s[c][0][3]));
#pragma unroll
      for (int jj = 1; jj < 4; ++jj)
        m = fmaxf(m, fmaxf(fmaxf(s[c][jj][0], s[c][jj][1]), fmaxf(s[c][jj][2], s[c][jj][3])));
      m = fmaxf(m, __shfl_xor(m, 16));
      m = fmaxf(m, __shfl_xor(m, 32));
      mx[c] = m;
    }
    const bool grow = (mx[0] > mcur[0] + 8.f) || (mx[1] > mcur[1] + 8.f);
    if (__any(grow)) {                     // defer-max (T13)
#pragma unroll
      for (int c = 0; c < 2; ++c) {
        const float mnew  = fmaxf(mcur[c], mx[c]);
        const float alpha = fexp2(mcur[c] - mnew);
        mcur[c] = mnew; lsum[c] *= alpha;
#pragma unroll
        for (int dj = 0; dj < 4; ++dj) o[c][dj] *= alpha;
      }
    }
#pragma unroll
    for (int c = 0; c < 2; ++c) {
      float ps = 0.f;
#pragma unroll
      for (int jj = 0; jj < 4; ++jj)
#pragma unroll
        for (int r = 0; r < 4; ++r) {
          const float p = fexp2(s[c][jj][r] - mcur[c]);
          s[c][jj][r] = p;
          ps += p;
        }
      ps += __shfl_xor(ps, 16);
      ps += __shfl_xor(ps, 32);
      lsum[c] += ps;
    }

    // ---- O^T += V^T P : P packed in-register (V kv-permuted at GEMM1) ----
#pragma unroll
    for (int kk2 = 0; kk2 < 2; ++kk2) {
      const int gran = kk2 * 4 + l4;
      int4 pw0, pw1;
      pw0.x = cvtpk(s[0][2 * kk2][0], s[0][2 * kk2][1]);
      pw0.y = cvtpk(s[0][2 * kk2][2], s[0][2 * kk2][3]);
      pw0.z = cvtpk(s[0][2 * kk2 + 1][0], s[0][2 * kk2 + 1][1]);
      pw0.w = cvtpk(s[0][2 * kk2 + 1][2], s[0][2 * kk2 + 1][3]);
      pw1.x = cvtpk(s[1][2 * kk2][0], s[1][2 * kk2][1]);
      pw1.y = cvtpk(s[1][2 * kk2][2], s[1][2 * kk2][3]);
      pw1.z = cvtpk(s[1][2 * kk2 + 1][0], s[1][2 * kk2 + 1][1]);
      pw1.w = cvtpk(s[1][2 * kk2 + 1][2], s[1][2 * kk2 + 1][3]);
      const bh8 pf0 = __builtin_bit_cast(bh8, pw0);
      const bh8 pf1 = __builtin_bit_cast(bh8, pw1);
      __builtin_amdgcn_s_setprio(1);
#pragma unroll
      for (int dj = 0; dj < 4; ++dj) {
        const int row = dj * 16 + l15;
        const bh8 vf =
            *(const bh8*)&SMEM[1][g][cur][row * 64 + ((gran ^ (row & 7)) * 8)];
        o[0][dj] = __builtin_amdgcn_mfma_f32_16x16x32_bf16(vf, pf0, o[0][dj], 0, 0, 0);
        o[1][dj] = __builtin_amdgcn_mfma_f32_16x16x32_bf16(vf, pf1, o[1][dj], 0, 0, 0);
      }
      __builtin_amdgcn_s_setprio(0);
    }

    __syncthreads();   // drains vmcnt(0): prefetched unit ready; buffer reuse safe
    cur ^= 1;
  }

  // ---- merge the two groups' partials (scratch aliased onto dead K/V LDS) --
  {
    float (*Mg)[64][37] = (float(*)[64][37]) & SMEM[0][0][0][0];  // 37.9KB <= 64KB
    if (g == 1) {
#pragma unroll
      for (int c = 0; c < 2; ++c)
#pragma unroll
        for (int dj = 0; dj < 4; ++dj)
#pragma unroll
          for (int r = 0; r < 4; ++r)
            Mg[wv][lane][c * 16 + dj * 4 + r] = o[c][dj][r];
      Mg[wv][lane][32] = mcur[0]; Mg[wv][lane][33] = mcur[1];
      Mg[wv][lane][34] = lsum[0]; Mg[wv][lane][35] = lsum[1];
    }
    __syncthreads();
    if (g == 0) {
#pragma unroll
      for (int c = 0; c < 2; ++c) {
        const float mb = Mg[wv][lane][32 + c];
        const float lb = Mg[wv][lane][34 + c];
        const float m  = fmaxf(mcur[c], mb);
        const float wa = fexp2(mcur[c] - m);
        const float wb = fexp2(mb - m);
        const float inv = 1.f / (lsum[c] * wa + lb * wb);
        const int t = qa * 128 + wv * 32 + c * 16 + l15;
#pragma unroll
        for (int dj = 0; dj < 4; ++dj) {
          const float* mo = &Mg[wv][lane][c * 16 + dj * 4];
          ushort4 hw;
          hw.x = f2bf((o[c][dj][0] * wa + mo[0] * wb) * inv);
          hw.y = f2bf((o[c][dj][1] * wa + mo[1] * wb) * inv);
          hw.z = f2bf((o[c][dj][2] * wa + mo[2] * wb) * inv);
          hw.w = f2bf((o[c][dj][3] * wa + mo[3] * wb) * inv);
          *(ushort4*)&Yb[((size_t)(b * T + t)) * C + h * HD + dj * 16 + l4 * 4] = hw;
        }
      }
    }
  }
}

extern "C" void kernel_launch(void* const* d_in, const int* in_sizes, int n_in,
                              void* d_out, int out_size, void* d_ws, size_t ws_size,
                              hipStream_t stream) {
  const float* x      = (const float*)d_in[0];
  const float* w_attn = (const float*)d_in[1];
  const float* b_attn = (const float*)d_in[2];
  const float* w_proj = (const float*)d_in[3];
  const float* b_proj = (const float*)d_in[4];
  float* out = (float*)d_out;

  unsigned short* xb  = (unsigned short*)d_ws;
  unsigned short* wab = xb  + (size_t)M * C;       // w_attn bf16 [3C][C]
  unsigned short* wpb = wab + (size_t)3 * C * C;   // w_proj bf16 [C][C]
  unsigned short* Qb  = wpb + (size_t)C * C;       // [BH][T][HD] (pre-scaled)
  unsigned short* Kb  = Qb  + (size_t)M * C;       // [BH][T][HD]
  unsigned short* Vb  = Kb  + (size_t)M * C;       // [BH][HD][T] transposed+permuted
  unsigned short* Yb  = xb;                        // alias: xb dead after GEMM1

  constexpr int CVT_BLOCKS = (M * C + 3 * C * C + C * C) / 1024;  // 8192
  cvt_all<<<dim3(CVT_BLOCKS), 256, 0, stream>>>(x, w_attn, w_proj, xb);

  gemm_bt<1><<<dim3(3 * C / 128, M / 128), 256, 0, stream>>>(
      xb, wab, b_attn, 3 * C, C, Qb, Kb, Vb, nullptr);

  attn<<<dim3(BH, 16), 512, 0, stream>>>(Qb, Kb, Vb, Yb);

  gemm_bt<0><<<dim3(C / 128, M / 128), 256, 0, stream>>>(
      Yb, wpb, b_proj, C, C, nullptr, nullptr, nullptr, out);
}

// Round 18
// 113.130 us; speedup vs baseline: 1.0290x; 1.0290x over previous
//
#include <hip/hip_runtime.h>
#include <hip/hip_bf16.h>

typedef __attribute__((ext_vector_type(4))) float f32x4;
typedef __attribute__((ext_vector_type(8))) short bh8;

#define DEVI static __device__ __forceinline__

constexpr int Bn = 2, T = 2048, C = 1024, H = 16, HD = 64;
constexpr int BH = Bn * H;   // 32
constexpr int M  = Bn * T;   // 4096
// fold 1/sqrt(HD) and log2(e) into Q so softmax uses exp2
constexpr float QSC = 0.125f * 1.44269504088896f;

DEVI unsigned short f2bf(float f) {
  unsigned int u = __builtin_bit_cast(unsigned int, f);
  u += 0x7FFFu + ((u >> 16) & 1u);   // RTNE
  return (unsigned short)(u >> 16);
}

DEVI unsigned int cvtpk(float lo, float hi) {  // 2xf32 -> packed 2xbf16 (1 VALU op)
  unsigned int r;
  asm("v_cvt_pk_bf16_f32 %0, %1, %2" : "=v"(r) : "v"(lo), "v"(hi));
  return r;
}

DEVI float fexp2(float x) {  // raw v_exp_f32 (2^x); CDNA has HW interlocks
  float r;
  asm("v_exp_f32 %0, %1" : "=v"(r) : "v"(x));
  return r;
}

DEVI void gload16(const void* g, void* l) {
  __builtin_amdgcn_global_load_lds((const __attribute__((address_space(1))) void*)g,
                                   (__attribute__((address_space(3))) void*)l,
                                   16, 0, 0);
}

// one fused fp32->bf16 convert for x | w_attn | w_proj (outputs contiguous in ws)
__global__ __launch_bounds__(256) void cvt_all(const float* __restrict__ x,
                                               const float* __restrict__ wa,
                                               const float* __restrict__ wp,
                                               unsigned short* __restrict__ out) {
  constexpr size_t n0 = (size_t)M * C;            // x
  constexpr size_t n1 = n0 + (size_t)3 * C * C;   // + w_attn
  const size_t i = ((size_t)blockIdx.x * 256 + threadIdx.x) * 4;
  const float* src;
  size_t off;
  if (i < n0)      { src = x;  off = i; }
  else if (i < n1) { src = wa; off = i - n0; }
  else             { src = wp; off = i - n1; }
  const float4 v = *(const float4*)(src + off);
  ushort4 o;
  o.x = f2bf(v.x); o.y = f2bf(v.y); o.z = f2bf(v.z); o.w = f2bf(v.w);
  *(ushort4*)(out + i) = o;
}

// C = A @ B^T (+bias). 128x128 tile, BK=64, 4 waves, 16x16x32 bf16 MFMA.
// R5-proven SINGLE-BUFFERED structure, DEFAULT block mapping (frozen:
// dbuf/8-phase/XCD-swizzle all regressed on this problem shape).
// EPI 0: fp32 out + bias. EPI 1: qkv scatter; V kv-PERMUTED (see attn).
template <int EPI>
__global__ __launch_bounds__(256) void gemm_bt(
    const unsigned short* __restrict__ A, const unsigned short* __restrict__ Bw,
    const float* __restrict__ bias, int N, int K,
    unsigned short* __restrict__ Qb, unsigned short* __restrict__ Kb,
    unsigned short* __restrict__ Vb, float* __restrict__ Outf) {
  __shared__ unsigned short As[128 * 64];
  __shared__ unsigned short Bs[128 * 64];

  const int tid  = threadIdx.x;
  const int lane = tid & 63;
  const int wid  = tid >> 6;
  const int wm = wid >> 1, wn = wid & 1;
  const int m0 = blockIdx.y * 128;
  const int n0 = blockIdx.x * 128;

  const int srow = lane >> 3;
  const int gp   = lane & 7;

  const unsigned short* Ab = A + (size_t)m0 * K;
  const unsigned short* Bb = Bw + (size_t)n0 * K;

  f32x4 acc[4][4] = {};

  for (int kt = 0; kt < K; kt += 64) {
    __syncthreads();
#pragma unroll
    for (int j = 0; j < 4; ++j) {
      const int row = wid * 32 + j * 8 + srow;
      const int gs  = gp ^ (row & 7);
      gload16(Ab + (size_t)row * K + kt + gs * 8, &As[(wid * 32 + j * 8) * 64]);
    }
#pragma unroll
    for (int j = 0; j < 4; ++j) {
      const int row = wid * 32 + j * 8 + srow;
      const int gs  = gp ^ (row & 7);
      gload16(Bb + (size_t)row * K + kt + gs * 8, &Bs[(wid * 32 + j * 8) * 64]);
    }
    __syncthreads();

#pragma unroll
    for (int kk = 0; kk < 2; ++kk) {
      bh8 af[4], bfr[4];
#pragma unroll
      for (int i = 0; i < 4; ++i) {
        const int row  = wm * 64 + i * 16 + (lane & 15);
        const int gran = kk * 4 + (lane >> 4);
        af[i] = *(const bh8*)&As[row * 64 + ((gran ^ (row & 7)) * 8)];
      }
#pragma unroll
      for (int j = 0; j < 4; ++j) {
        const int row  = wn * 64 + j * 16 + (lane & 15);
        const int gran = kk * 4 + (lane >> 4);
        bfr[j] = *(const bh8*)&Bs[row * 64 + ((gran ^ (row & 7)) * 8)];
      }
#pragma unroll
      for (int i = 0; i < 4; ++i)
#pragma unroll
        for (int j = 0; j < 4; ++j)
          acc[i][j] = __builtin_amdgcn_mfma_f32_16x16x32_bf16(af[i], bfr[j],
                                                              acc[i][j], 0, 0, 0);
    }
  }

  const int rbase = m0 + wm * 64 + ((lane >> 4) << 2);
  const int cbase = n0 + wn * 64 + (lane & 15);

  if (EPI == 0) {
#pragma unroll
    for (int j = 0; j < 4; ++j) {
      const int n = cbase + j * 16;
      const float bv = bias[n];
#pragma unroll
      for (int i = 0; i < 4; ++i)
#pragma unroll
        for (int r = 0; r < 4; ++r) {
          const int m = rbase + i * 16 + r;
          Outf[(size_t)m * N + n] = acc[i][j][r] + bv;
        }
    }
  } else {
#pragma unroll
    for (int j = 0; j < 4; ++j) {
      const int n = cbase + j * 16;
      const float bv = bias[n];
      const int part = n >> 10;      // 0:q 1:k 2:v
      const int nn = n & 1023;
      const int h = nn >> 6, d = nn & 63;
#pragma unroll
      for (int i = 0; i < 4; ++i)
#pragma unroll
        for (int r = 0; r < 4; ++r) {
          const int m = rbase + i * 16 + r;
          const int b = m >> 11, t = m & (T - 1);
          const int bh = b * H + h;
          const float val = acc[i][j][r] + bv;
          if (part == 0)
            Qb[((size_t)(bh * T + t)) * HD + d] = f2bf(val * QSC);
          else if (part == 1)
            Kb[((size_t)(bh * T + t)) * HD + d] = f2bf(val);
          else {
            // kv-permutation (bits 0..4 only -> valid for any KVBLK>=32):
            // kp=[..|b1|l4|r] -> kap=[..|l4|b1|r]
            const int kp  = t & 127;
            const int kap = (kp & ~31) | (((kp >> 2) & 3) << 3) |
                            (((kp >> 4) & 1) << 2) | (kp & 3);
            const int tp  = (t & ~127) | kap;
            Vb[((size_t)(bh * HD + d)) * T + tp] = f2bf(val);  // transposed+permuted
          }
        }
    }
  }
}

// ---------------------------------------------------------------------------
// Flash attention, causal. Grid: (BH=32, 8). Block: 512 thr = 8 waves.
// FINAL = R10/R13/R16 attn (thrice-verified best; 9 variants tried).
// kv-PARITY WAVE-GROUP SPLIT: group g = waves [4g,4g+4) processes kv units
// (KVBLK=64) of parity g over the full 128-q tile (32 q/wave: each ds_read
// feeds 2 MFMAs), own dbuf K/V LDS + own online-softmax state. Pass unit
// counts (2qa+2, 32-2qa) are even -> lockstep via plain __syncthreads.
// Pass-end in-LDS split-kv merge (group0 writes Yb). 17 sequential iters at
// 2 waves/SIMD. Swapped QK^T, in-register P via cvtpk (V kv-permuted at
// GEMM1), defer-max (T13), raw v_exp_f32.
// ---------------------------------------------------------------------------
__global__ __launch_bounds__(512, 2) void attn(
    const unsigned short* __restrict__ Qb, const unsigned short* __restrict__ Kb,
    const unsigned short* __restrict__ Vb, unsigned short* __restrict__ Yb) {
  __shared__ unsigned short Ks[2][2][64 * 64];   // [group][dbuf]
  __shared__ unsigned short Vs[2][2][64 * 64];
  __shared__ float Mg[4][64][37];                // merge scratch (+1 pad: no conflicts)

  const int tid  = threadIdx.x;
  const int lane = tid & 63;
  const int wid  = tid >> 6;          // 0..7
  const int g    = wid >> 2;          // kv-parity group
  const int wv   = wid & 3;           // wave within group
  const int bh   = blockIdx.x;
  const int b = bh >> 4, h = bh & 15;
  const int qa = blockIdx.y;          // 0..7 ; paired tile = 15-qa
  const int p0n = qa + 1;             // local iters in pass 0 (per group); total 17

  const int l4  = lane >> 4;          // 0..3
  const int l15 = lane & 15;

  const unsigned short* Kbh = Kb + (size_t)bh * T * HD;
  const unsigned short* Vbh = Vb + (size_t)bh * HD * T;

  const int sr = lane >> 3, sg = lane & 7;

  // Q fragments (B-operand), 2 chunks x 2 kk (identical for both groups)
  bh8 qk[2][2];
  auto loadQ = [&](int tile) {
#pragma unroll
    for (int c = 0; c < 2; ++c) {
      const size_t qo =
          ((size_t)(bh * T + tile * 128 + wv * 32 + c * 16 + l15)) * HD + l4 * 8;
      qk[c][0] = *(const bh8*)&Qb[qo];
      qk[c][1] = *(const bh8*)&Qb[qo + 32];
    }
  };
  loadQ(qa);

  f32x4 o[2][4] = {};
  float mcur[2] = {-1e30f, -1e30f}, lsum[2] = {0.f, 0.f};

  auto stage = [&](int buf, int kt) {
#pragma unroll
    for (int sl = 0; sl < 2; ++sl) {
      const int row = wv * 16 + sl * 8 + sr;
      const int gs  = sg ^ (row & 7);
      gload16(Kbh + (size_t)(kt + row) * HD + gs * 8,
              &Ks[g][buf][(wv * 16 + sl * 8) * 64]);
      gload16(Vbh + (size_t)row * T + kt + gs * 8,
              &Vs[g][buf][(wv * 16 + sl * 8) * 64]);
    }
  };

  // merge the two groups' partials for tile qt; group0 writes Yb
  auto flush = [&](int qt) {
    __syncthreads();
    if (g == 1) {
#pragma unroll
      for (int c = 0; c < 2; ++c)
#pragma unroll
        for (int dj = 0; dj < 4; ++dj)
#pragma unroll
          for (int r = 0; r < 4; ++r)
            Mg[wv][lane][c * 16 + dj * 4 + r] = o[c][dj][r];
      Mg[wv][lane][32] = mcur[0]; Mg[wv][lane][33] = mcur[1];
      Mg[wv][lane][34] = lsum[0]; Mg[wv][lane][35] = lsum[1];
    }
    __syncthreads();
    if (g == 0) {
#pragma unroll
      for (int c = 0; c < 2; ++c) {
        const float mb = Mg[wv][lane][32 + c];
        const float lb = Mg[wv][lane][34 + c];
        const float m  = fmaxf(mcur[c], mb);
        const float wa = fexp2(mcur[c] - m);
        const float wb = fexp2(mb - m);
        const float inv = 1.f / (lsum[c] * wa + lb * wb);
        const int t = qt * 128 + wv * 32 + c * 16 + l15;
#pragma unroll
        for (int dj = 0; dj < 4; ++dj) {
          const float* mo = &Mg[wv][lane][c * 16 + dj * 4];
          ushort4 hw;
          hw.x = f2bf((o[c][dj][0] * wa + mo[0] * wb) * inv);
          hw.y = f2bf((o[c][dj][1] * wa + mo[1] * wb) * inv);
          hw.z = f2bf((o[c][dj][2] * wa + mo[2] * wb) * inv);
          hw.w = f2bf((o[c][dj][3] * wa + mo[3] * wb) * inv);
          *(ushort4*)&Yb[((size_t)(b * T + t)) * C + h * HD + dj * 16 + l4 * 4] = hw;
        }
      }
    }
    __syncthreads();
  };

  // prologue: stage this group's unit 0 (kv parity g) into buffer 0
  stage(0, g * 64);
  __syncthreads();

  int cur = 0;
  for (int i = 0; i < 17; ++i) {
    // ---- pass boundary: merge+flush tile qa, reset, switch Q ----
    if (i == p0n) {
      flush(qa);
      mcur[0] = mcur[1] = -1e30f; lsum[0] = lsum[1] = 0.f;
#pragma unroll
      for (int c = 0; c < 2; ++c)
#pragma unroll
        for (int dj = 0; dj < 4; ++dj) o[c][dj] = f32x4{0.f, 0.f, 0.f, 0.f};
      loadQ(15 - qa);
    }

    // ---- prefetch this group's next unit ----
    if (i < 16) {
      const int ni  = i + 1;
      const int nli = (ni >= p0n) ? ni - p0n : ni;
      stage(cur ^ 1, (2 * nli + g) * 64);
    }

    const int li = (i >= p0n) ? i - p0n : i;
    const int qt = (i >= p0n) ? 15 - qa : qa;
    const int kt = (2 * li + g) * 64;   // absolute kv offset of this unit

    // ---- S^T = K Q^T : s[c][j][r] = S[kv=kt+j*16+l4*4+r][q=..+c*16+l15] ----
    f32x4 s[2][4] = {};
#pragma unroll
    for (int kk = 0; kk < 2; ++kk) {
      __builtin_amdgcn_s_setprio(1);
#pragma unroll
      for (int j = 0; j < 4; ++j) {
        const int row  = j * 16 + l15;
        const int gran = kk * 4 + l4;
        const bh8 kfr = *(const bh8*)&Ks[g][cur][row * 64 + ((gran ^ (row & 7)) * 8)];
        s[0][j] = __builtin_amdgcn_mfma_f32_16x16x32_bf16(kfr, qk[0][kk], s[0][j], 0, 0, 0);
        s[1][j] = __builtin_amdgcn_mfma_f32_16x16x32_bf16(kfr, qk[1][kk], s[1][j], 0, 0, 0);
      }
      __builtin_amdgcn_s_setprio(0);
    }

    // ---- causal mask (diag-touching units only) ----
    if (kt >= qt * 128) {
      const int kbase = kt - qt * 128;
#pragma unroll
      for (int c = 0; c < 2; ++c) {
        const int qloc = wv * 32 + c * 16 + l15;
#pragma unroll
        for (int j = 0; j < 4; ++j)
#pragma unroll
          for (int r = 0; r < 4; ++r) {
            const int kvl = kbase + j * 16 + l4 * 4 + r;
            if (kvl > qloc) s[c][j][r] = -1e30f;
          }
      }
    }

    // ---- online softmax: per-lane rows (one per chunk), 2 shuffles each ----
    float mx[2];
#pragma unroll
    for (int c = 0; c < 2; ++c) {
      float m = fmaxf(fmaxf(s[c][0][0], s[c][0][1]), fmaxf(s[c][0][2], s[c][0][3]));
#pragma unroll
      for (int j = 1; j < 4; ++j)
        m = fmaxf(m, fmaxf(fmaxf(s[c][j][0], s[c][j][1]), fmaxf(s[c][j][2], s[c][j][3])));
      m = fmaxf(m, __shfl_xor(m, 16));
      m = fmaxf(m, __shfl_xor(m, 32));
      mx[c] = m;
    }
    const bool grow = (mx[0] > mcur[0] + 8.f) || (mx[1] > mcur[1] + 8.f);
    if (__any(grow)) {                     // defer-max (T13)
#pragma unroll
      for (int c = 0; c < 2; ++c) {
        const float mnew  = fmaxf(mcur[c], mx[c]);
        const float alpha = fexp2(mcur[c] - mnew);
        mcur[c] = mnew; lsum[c] *= alpha;
#pragma unroll
        for (int dj = 0; dj < 4; ++dj) o[c][dj] *= alpha;
      }
    }
#pragma unroll
    for (int c = 0; c < 2; ++c) {
      float ps = 0.f;
#pragma unroll
      for (int j = 0; j < 4; ++j)
#pragma unroll
        for (int r = 0; r < 4; ++r) {
          const float p = fexp2(s[c][j][r] - mcur[c]);
          s[c][j][r] = p;
          ps += p;
        }
      ps += __shfl_xor(ps, 16);
      ps += __shfl_xor(ps, 32);
      lsum[c] += ps;
    }

    // ---- O^T += V^T P : P packed in-register (V kv-permuted at GEMM1) ----
#pragma unroll
    for (int kk2 = 0; kk2 < 2; ++kk2) {
      const int gran = kk2 * 4 + l4;
      int4 pw0, pw1;
      pw0.x = cvtpk(s[0][2 * kk2][0], s[0][2 * kk2][1]);
      pw0.y = cvtpk(s[0][2 * kk2][2], s[0][2 * kk2][3]);
      pw0.z = cvtpk(s[0][2 * kk2 + 1][0], s[0][2 * kk2 + 1][1]);
      pw0.w = cvtpk(s[0][2 * kk2 + 1][2], s[0][2 * kk2 + 1][3]);
      pw1.x = cvtpk(s[1][2 * kk2][0], s[1][2 * kk2][1]);
      pw1.y = cvtpk(s[1][2 * kk2][2], s[1][2 * kk2][3]);
      pw1.z = cvtpk(s[1][2 * kk2 + 1][0], s[1][2 * kk2 + 1][1]);
      pw1.w = cvtpk(s[1][2 * kk2 + 1][2], s[1][2 * kk2 + 1][3]);
      const bh8 pf0 = __builtin_bit_cast(bh8, pw0);
      const bh8 pf1 = __builtin_bit_cast(bh8, pw1);
      __builtin_amdgcn_s_setprio(1);
#pragma unroll
      for (int dj = 0; dj < 4; ++dj) {
        const int row = dj * 16 + l15;
        const bh8 vf = *(const bh8*)&Vs[g][cur][row * 64 + ((gran ^ (row & 7)) * 8)];
        o[0][dj] = __builtin_amdgcn_mfma_f32_16x16x32_bf16(vf, pf0, o[0][dj], 0, 0, 0);
        o[1][dj] = __builtin_amdgcn_mfma_f32_16x16x32_bf16(vf, pf1, o[1][dj], 0, 0, 0);
      }
      __builtin_amdgcn_s_setprio(0);
    }

    __syncthreads();   // drains vmcnt(0): prefetched unit ready; buffer reuse safe
    cur ^= 1;
  }

  // ---- merge+flush pass-1 tile ----
  flush(15 - qa);
}

extern "C" void kernel_launch(void* const* d_in, const int* in_sizes, int n_in,
                              void* d_out, int out_size, void* d_ws, size_t ws_size,
                              hipStream_t stream) {
  const float* x      = (const float*)d_in[0];
  const float* w_attn = (const float*)d_in[1];
  const float* b_attn = (const float*)d_in[2];
  const float* w_proj = (const float*)d_in[3];
  const float* b_proj = (const float*)d_in[4];
  float* out = (float*)d_out;

  unsigned short* xb  = (unsigned short*)d_ws;
  unsigned short* wab = xb  + (size_t)M * C;       // w_attn bf16 [3C][C]
  unsigned short* wpb = wab + (size_t)3 * C * C;   // w_proj bf16 [C][C]
  unsigned short* Qb  = wpb + (size_t)C * C;       // [BH][T][HD] (pre-scaled)
  unsigned short* Kb  = Qb  + (size_t)M * C;       // [BH][T][HD]
  unsigned short* Vb  = Kb  + (size_t)M * C;       // [BH][HD][T] transposed+permuted
  unsigned short* Yb  = xb;                        // alias: xb dead after GEMM1

  constexpr int CVT_BLOCKS = (M * C + 3 * C * C + C * C) / 1024;  // 8192
  cvt_all<<<dim3(CVT_BLOCKS), 256, 0, stream>>>(x, w_attn, w_proj, xb);

  gemm_bt<1><<<dim3(3 * C / 128, M / 128), 256, 0, stream>>>(
      xb, wab, b_attn, 3 * C, C, Qb, Kb, Vb, nullptr);

  attn<<<dim3(BH, 8), 512, 0, stream>>>(Qb, Kb, Vb, Yb);

  gemm_bt<0><<<dim3(C / 128, M / 128), 256, 0, stream>>>(
      Yb, wpb, b_proj, C, C, nullptr, nullptr, nullptr, out);
}

// Round 19
// 105.534 us; speedup vs baseline: 1.1031x; 1.0720x over previous
//
#include <hip/hip_runtime.h>
#include <hip/hip_bf16.h>

typedef __attribute__((ext_vector_type(4))) float f32x4;
typedef __attribute__((ext_vector_type(8))) short bh8;

#define DEVI static __device__ __forceinline__

constexpr int Bn = 2, T = 2048, C = 1024, H = 16, HD = 64;
constexpr int BH = Bn * H;   // 32
constexpr int M  = Bn * T;   // 4096
// fold 1/sqrt(HD) and log2(e) into Q so softmax uses exp2
constexpr float QSC = 0.125f * 1.44269504088896f;

DEVI unsigned short f2bf(float f) {
  unsigned int u = __builtin_bit_cast(unsigned int, f);
  u += 0x7FFFu + ((u >> 16) & 1u);   // RTNE
  return (unsigned short)(u >> 16);
}

DEVI unsigned int cvtpk(float lo, float hi) {  // 2xf32 -> packed 2xbf16 (1 VALU op)
  unsigned int r;
  asm("v_cvt_pk_bf16_f32 %0, %1, %2" : "=v"(r) : "v"(lo), "v"(hi));
  return r;
}

DEVI float fexp2(float x) {  // raw v_exp_f32 (2^x); CDNA has HW interlocks
  float r;
  asm("v_exp_f32 %0, %1" : "=v"(r) : "v"(x));
  return r;
}

DEVI void gload16(const void* g, void* l) {
  __builtin_amdgcn_global_load_lds((const __attribute__((address_space(1))) void*)g,
                                   (__attribute__((address_space(3))) void*)l,
                                   16, 0, 0);
}

// one fused fp32->bf16 convert for x | w_attn | w_proj (outputs contiguous in ws)
__global__ __launch_bounds__(256) void cvt_all(const float* __restrict__ x,
                                               const float* __restrict__ wa,
                                               const float* __restrict__ wp,
                                               unsigned short* __restrict__ out) {
  constexpr size_t n0 = (size_t)M * C;            // x
  constexpr size_t n1 = n0 + (size_t)3 * C * C;   // + w_attn
  const size_t i = ((size_t)blockIdx.x * 256 + threadIdx.x) * 4;
  const float* src;
  size_t off;
  if (i < n0)      { src = x;  off = i; }
  else if (i < n1) { src = wa; off = i - n0; }
  else             { src = wp; off = i - n1; }
  const float4 v = *(const float4*)(src + off);
  ushort4 o;
  o.x = f2bf(v.x); o.y = f2bf(v.y); o.z = f2bf(v.z); o.w = f2bf(v.w);
  *(ushort4*)(out + i) = o;
}

// C = A @ B^T (+bias). 128x128 tile, BK=64, 16x16x32 bf16 MFMA.
// R19: SAME memory structure as the R5-proven single-buffered kernel (same
// staging, same LDS layout/swizzle, same barriers, same grid) but 8 WAVES
// per block (wave = 32x64 sub-tile, acc[2][4]) instead of 4: waves/CU at
// 3 blocks/CU rises 12 -> 24, doubling the m114 cross-block overlap pool
// that hides each block's staging drain. LDS-read traffic x1.5 (far from
// the LDS ceiling). launch_bounds(512,6) caps VGPR at 85 (est ~65).
// EPI 0: fp32 out + bias. EPI 1: qkv scatter; V kv-PERMUTED (see attn).
template <int EPI>
__global__ __launch_bounds__(512, 6) void gemm_bt(
    const unsigned short* __restrict__ A, const unsigned short* __restrict__ Bw,
    const float* __restrict__ bias, int N, int K,
    unsigned short* __restrict__ Qb, unsigned short* __restrict__ Kb,
    unsigned short* __restrict__ Vb, float* __restrict__ Outf) {
  __shared__ unsigned short As[128 * 64];
  __shared__ unsigned short Bs[128 * 64];

  const int tid  = threadIdx.x;
  const int lane = tid & 63;
  const int wid  = tid >> 6;          // 0..7
  const int wm = wid >> 1, wn = wid & 1;  // 4x2 wave grid: 32-row x 64-col
  const int m0 = blockIdx.y * 128;
  const int n0 = blockIdx.x * 128;
  const int l15 = lane & 15, l4 = lane >> 4;

  const int srow = lane >> 3;
  const int gp   = lane & 7;

  const unsigned short* Ab = A + (size_t)m0 * K;
  const unsigned short* Bb = Bw + (size_t)n0 * K;

  f32x4 acc[2][4] = {};

  for (int kt = 0; kt < K; kt += 64) {
    __syncthreads();
#pragma unroll
    for (int sl = 0; sl < 2; ++sl) {     // 8 waves x 2 slabs x 8 rows = 128 rows
      const int row = wid * 16 + sl * 8 + srow;
      const int gs  = gp ^ (row & 7);
      gload16(Ab + (size_t)row * K + kt + gs * 8, &As[(wid * 16 + sl * 8) * 64]);
      gload16(Bb + (size_t)row * K + kt + gs * 8, &Bs[(wid * 16 + sl * 8) * 64]);
    }
    __syncthreads();

#pragma unroll
    for (int kk = 0; kk < 2; ++kk) {
      bh8 af[2], bfr[4];
#pragma unroll
      for (int i = 0; i < 2; ++i) {
        const int row  = wm * 32 + i * 16 + l15;
        const int gran = kk * 4 + l4;
        af[i] = *(const bh8*)&As[row * 64 + ((gran ^ (row & 7)) * 8)];
      }
#pragma unroll
      for (int j = 0; j < 4; ++j) {
        const int row  = wn * 64 + j * 16 + l15;
        const int gran = kk * 4 + l4;
        bfr[j] = *(const bh8*)&Bs[row * 64 + ((gran ^ (row & 7)) * 8)];
      }
#pragma unroll
      for (int i = 0; i < 2; ++i)
#pragma unroll
        for (int j = 0; j < 4; ++j)
          acc[i][j] = __builtin_amdgcn_mfma_f32_16x16x32_bf16(af[i], bfr[j],
                                                              acc[i][j], 0, 0, 0);
    }
  }

  const int rbase = m0 + wm * 32 + (l4 << 2);
  const int cbase = n0 + wn * 64 + l15;

  if (EPI == 0) {
#pragma unroll
    for (int j = 0; j < 4; ++j) {
      const int n = cbase + j * 16;
      const float bv = bias[n];
#pragma unroll
      for (int i = 0; i < 2; ++i)
#pragma unroll
        for (int r = 0; r < 4; ++r) {
          const int m = rbase + i * 16 + r;
          Outf[(size_t)m * N + n] = acc[i][j][r] + bv;
        }
    }
  } else {
#pragma unroll
    for (int j = 0; j < 4; ++j) {
      const int n = cbase + j * 16;
      const float bv = bias[n];
      const int part = n >> 10;      // 0:q 1:k 2:v
      const int nn = n & 1023;
      const int h = nn >> 6, d = nn & 63;
#pragma unroll
      for (int i = 0; i < 2; ++i)
#pragma unroll
        for (int r = 0; r < 4; ++r) {
          const int m = rbase + i * 16 + r;
          const int b = m >> 11, t = m & (T - 1);
          const int bh = b * H + h;
          const float val = acc[i][j][r] + bv;
          if (part == 0)
            Qb[((size_t)(bh * T + t)) * HD + d] = f2bf(val * QSC);
          else if (part == 1)
            Kb[((size_t)(bh * T + t)) * HD + d] = f2bf(val);
          else {
            // kv-permutation (bits 0..4 only -> valid for any KVBLK>=32):
            // kp=[..|b1|l4|r] -> kap=[..|l4|b1|r]
            const int kp  = t & 127;
            const int kap = (kp & ~31) | (((kp >> 2) & 3) << 3) |
                            (((kp >> 4) & 1) << 2) | (kp & 3);
            const int tp  = (t & ~127) | kap;
            Vb[((size_t)(bh * HD + d)) * T + tp] = f2bf(val);  // transposed+permuted
          }
        }
    }
  }
}

// ---------------------------------------------------------------------------
// Flash attention, causal. Grid: (BH=32, 8). Block: 512 thr = 8 waves.
// R10/R13/R16 attn (4x-verified best; 9 variants tried) - UNCHANGED.
// kv-PARITY WAVE-GROUP SPLIT: group g = waves [4g,4g+4) processes kv units
// (KVBLK=64) of parity g over the full 128-q tile (32 q/wave: each ds_read
// feeds 2 MFMAs), own dbuf K/V LDS + own online-softmax state. Pass unit
// counts (2qa+2, 32-2qa) are even -> lockstep via plain __syncthreads.
// Pass-end in-LDS split-kv merge (group0 writes Yb). 17 sequential iters at
// 2 waves/SIMD. Swapped QK^T, in-register P via cvtpk (V kv-permuted at
// GEMM1), defer-max (T13), raw v_exp_f32.
// ---------------------------------------------------------------------------
__global__ __launch_bounds__(512, 2) void attn(
    const unsigned short* __restrict__ Qb, const unsigned short* __restrict__ Kb,
    const unsigned short* __restrict__ Vb, unsigned short* __restrict__ Yb) {
  __shared__ unsigned short Ks[2][2][64 * 64];   // [group][dbuf]
  __shared__ unsigned short Vs[2][2][64 * 64];
  __shared__ float Mg[4][64][37];                // merge scratch (+1 pad: no conflicts)

  const int tid  = threadIdx.x;
  const int lane = tid & 63;
  const int wid  = tid >> 6;          // 0..7
  const int g    = wid >> 2;          // kv-parity group
  const int wv   = wid & 3;           // wave within group
  const int bh   = blockIdx.x;
  const int b = bh >> 4, h = bh & 15;
  const int qa = blockIdx.y;          // 0..7 ; paired tile = 15-qa
  const int p0n = qa + 1;             // local iters in pass 0 (per group); total 17

  const int l4  = lane >> 4;          // 0..3
  const int l15 = lane & 15;

  const unsigned short* Kbh = Kb + (size_t)bh * T * HD;
  const unsigned short* Vbh = Vb + (size_t)bh * HD * T;

  const int sr = lane >> 3, sg = lane & 7;

  // Q fragments (B-operand), 2 chunks x 2 kk (identical for both groups)
  bh8 qk[2][2];
  auto loadQ = [&](int tile) {
#pragma unroll
    for (int c = 0; c < 2; ++c) {
      const size_t qo =
          ((size_t)(bh * T + tile * 128 + wv * 32 + c * 16 + l15)) * HD + l4 * 8;
      qk[c][0] = *(const bh8*)&Qb[qo];
      qk[c][1] = *(const bh8*)&Qb[qo + 32];
    }
  };
  loadQ(qa);

  f32x4 o[2][4] = {};
  float mcur[2] = {-1e30f, -1e30f}, lsum[2] = {0.f, 0.f};

  auto stage = [&](int buf, int kt) {
#pragma unroll
    for (int sl = 0; sl < 2; ++sl) {
      const int row = wv * 16 + sl * 8 + sr;
      const int gs  = sg ^ (row & 7);
      gload16(Kbh + (size_t)(kt + row) * HD + gs * 8,
              &Ks[g][buf][(wv * 16 + sl * 8) * 64]);
      gload16(Vbh + (size_t)row * T + kt + gs * 8,
              &Vs[g][buf][(wv * 16 + sl * 8) * 64]);
    }
  };

  // merge the two groups' partials for tile qt; group0 writes Yb
  auto flush = [&](int qt) {
    __syncthreads();
    if (g == 1) {
#pragma unroll
      for (int c = 0; c < 2; ++c)
#pragma unroll
        for (int dj = 0; dj < 4; ++dj)
#pragma unroll
          for (int r = 0; r < 4; ++r)
            Mg[wv][lane][c * 16 + dj * 4 + r] = o[c][dj][r];
      Mg[wv][lane][32] = mcur[0]; Mg[wv][lane][33] = mcur[1];
      Mg[wv][lane][34] = lsum[0]; Mg[wv][lane][35] = lsum[1];
    }
    __syncthreads();
    if (g == 0) {
#pragma unroll
      for (int c = 0; c < 2; ++c) {
        const float mb = Mg[wv][lane][32 + c];
        const float lb = Mg[wv][lane][34 + c];
        const float m  = fmaxf(mcur[c], mb);
        const float wa = fexp2(mcur[c] - m);
        const float wb = fexp2(mb - m);
        const float inv = 1.f / (lsum[c] * wa + lb * wb);
        const int t = qt * 128 + wv * 32 + c * 16 + l15;
#pragma unroll
        for (int dj = 0; dj < 4; ++dj) {
          const float* mo = &Mg[wv][lane][c * 16 + dj * 4];
          ushort4 hw;
          hw.x = f2bf((o[c][dj][0] * wa + mo[0] * wb) * inv);
          hw.y = f2bf((o[c][dj][1] * wa + mo[1] * wb) * inv);
          hw.z = f2bf((o[c][dj][2] * wa + mo[2] * wb) * inv);
          hw.w = f2bf((o[c][dj][3] * wa + mo[3] * wb) * inv);
          *(ushort4*)&Yb[((size_t)(b * T + t)) * C + h * HD + dj * 16 + l4 * 4] = hw;
        }
      }
    }
    __syncthreads();
  };

  // prologue: stage this group's unit 0 (kv parity g) into buffer 0
  stage(0, g * 64);
  __syncthreads();

  int cur = 0;
  for (int i = 0; i < 17; ++i) {
    // ---- pass boundary: merge+flush tile qa, reset, switch Q ----
    if (i == p0n) {
      flush(qa);
      mcur[0] = mcur[1] = -1e30f; lsum[0] = lsum[1] = 0.f;
#pragma unroll
      for (int c = 0; c < 2; ++c)
#pragma unroll
        for (int dj = 0; dj < 4; ++dj) o[c][dj] = f32x4{0.f, 0.f, 0.f, 0.f};
      loadQ(15 - qa);
    }

    // ---- prefetch this group's next unit ----
    if (i < 16) {
      const int ni  = i + 1;
      const int nli = (ni >= p0n) ? ni - p0n : ni;
      stage(cur ^ 1, (2 * nli + g) * 64);
    }

    const int li = (i >= p0n) ? i - p0n : i;
    const int qt = (i >= p0n) ? 15 - qa : qa;
    const int kt = (2 * li + g) * 64;   // absolute kv offset of this unit

    // ---- S^T = K Q^T : s[c][j][r] = S[kv=kt+j*16+l4*4+r][q=..+c*16+l15] ----
    f32x4 s[2][4] = {};
#pragma unroll
    for (int kk = 0; kk < 2; ++kk) {
      __builtin_amdgcn_s_setprio(1);
#pragma unroll
      for (int j = 0; j < 4; ++j) {
        const int row  = j * 16 + l15;
        const int gran = kk * 4 + l4;
        const bh8 kfr = *(const bh8*)&Ks[g][cur][row * 64 + ((gran ^ (row & 7)) * 8)];
        s[0][j] = __builtin_amdgcn_mfma_f32_16x16x32_bf16(kfr, qk[0][kk], s[0][j], 0, 0, 0);
        s[1][j] = __builtin_amdgcn_mfma_f32_16x16x32_bf16(kfr, qk[1][kk], s[1][j], 0, 0, 0);
      }
      __builtin_amdgcn_s_setprio(0);
    }

    // ---- causal mask (diag-touching units only) ----
    if (kt >= qt * 128) {
      const int kbase = kt - qt * 128;
#pragma unroll
      for (int c = 0; c < 2; ++c) {
        const int qloc = wv * 32 + c * 16 + l15;
#pragma unroll
        for (int j = 0; j < 4; ++j)
#pragma unroll
          for (int r = 0; r < 4; ++r) {
            const int kvl = kbase + j * 16 + l4 * 4 + r;
            if (kvl > qloc) s[c][j][r] = -1e30f;
          }
      }
    }

    // ---- online softmax: per-lane rows (one per chunk), 2 shuffles each ----
    float mx[2];
#pragma unroll
    for (int c = 0; c < 2; ++c) {
      float m = fmaxf(fmaxf(s[c][0][0], s[c][0][1]), fmaxf(s[c][0][2], s[c][0][3]));
#pragma unroll
      for (int j = 1; j < 4; ++j)
        m = fmaxf(m, fmaxf(fmaxf(s[c][j][0], s[c][j][1]), fmaxf(s[c][j][2], s[c][j][3])));
      m = fmaxf(m, __shfl_xor(m, 16));
      m = fmaxf(m, __shfl_xor(m, 32));
      mx[c] = m;
    }
    const bool grow = (mx[0] > mcur[0] + 8.f) || (mx[1] > mcur[1] + 8.f);
    if (__any(grow)) {                     // defer-max (T13)
#pragma unroll
      for (int c = 0; c < 2; ++c) {
        const float mnew  = fmaxf(mcur[c], mx[c]);
        const float alpha = fexp2(mcur[c] - mnew);
        mcur[c] = mnew; lsum[c] *= alpha;
#pragma unroll
        for (int dj = 0; dj < 4; ++dj) o[c][dj] *= alpha;
      }
    }
#pragma unroll
    for (int c = 0; c < 2; ++c) {
      float ps = 0.f;
#pragma unroll
      for (int j = 0; j < 4; ++j)
#pragma unroll
        for (int r = 0; r < 4; ++r) {
          const float p = fexp2(s[c][j][r] - mcur[c]);
          s[c][j][r] = p;
          ps += p;
        }
      ps += __shfl_xor(ps, 16);
      ps += __shfl_xor(ps, 32);
      lsum[c] += ps;
    }

    // ---- O^T += V^T P : P packed in-register (V kv-permuted at GEMM1) ----
#pragma unroll
    for (int kk2 = 0; kk2 < 2; ++kk2) {
      const int gran = kk2 * 4 + l4;
      int4 pw0, pw1;
      pw0.x = cvtpk(s[0][2 * kk2][0], s[0][2 * kk2][1]);
      pw0.y = cvtpk(s[0][2 * kk2][2], s[0][2 * kk2][3]);
      pw0.z = cvtpk(s[0][2 * kk2 + 1][0], s[0][2 * kk2 + 1][1]);
      pw0.w = cvtpk(s[0][2 * kk2 + 1][2], s[0][2 * kk2 + 1][3]);
      pw1.x = cvtpk(s[1][2 * kk2][0], s[1][2 * kk2][1]);
      pw1.y = cvtpk(s[1][2 * kk2][2], s[1][2 * kk2][3]);
      pw1.z = cvtpk(s[1][2 * kk2 + 1][0], s[1][2 * kk2 + 1][1]);
      pw1.w = cvtpk(s[1][2 * kk2 + 1][2], s[1][2 * kk2 + 1][3]);
      const bh8 pf0 = __builtin_bit_cast(bh8, pw0);
      const bh8 pf1 = __builtin_bit_cast(bh8, pw1);
      __builtin_amdgcn_s_setprio(1);
#pragma unroll
      for (int dj = 0; dj < 4; ++dj) {
        const int row = dj * 16 + l15;
        const bh8 vf = *(const bh8*)&Vs[g][cur][row * 64 + ((gran ^ (row & 7)) * 8)];
        o[0][dj] = __builtin_amdgcn_mfma_f32_16x16x32_bf16(vf, pf0, o[0][dj], 0, 0, 0);
        o[1][dj] = __builtin_amdgcn_mfma_f32_16x16x32_bf16(vf, pf1, o[1][dj], 0, 0, 0);
      }
      __builtin_amdgcn_s_setprio(0);
    }

    __syncthreads();   // drains vmcnt(0): prefetched unit ready; buffer reuse safe
    cur ^= 1;
  }

  // ---- merge+flush pass-1 tile ----
  flush(15 - qa);
}

extern "C" void kernel_launch(void* const* d_in, const int* in_sizes, int n_in,
                              void* d_out, int out_size, void* d_ws, size_t ws_size,
                              hipStream_t stream) {
  const float* x      = (const float*)d_in[0];
  const float* w_attn = (const float*)d_in[1];
  const float* b_attn = (const float*)d_in[2];
  const float* w_proj = (const float*)d_in[3];
  const float* b_proj = (const float*)d_in[4];
  float* out = (float*)d_out;

  unsigned short* xb  = (unsigned short*)d_ws;
  unsigned short* wab = xb  + (size_t)M * C;       // w_attn bf16 [3C][C]
  unsigned short* wpb = wab + (size_t)3 * C * C;   // w_proj bf16 [C][C]
  unsigned short* Qb  = wpb + (size_t)C * C;       // [BH][T][HD] (pre-scaled)
  unsigned short* Kb  = Qb  + (size_t)M * C;       // [BH][T][HD]
  unsigned short* Vb  = Kb  + (size_t)M * C;       // [BH][HD][T] transposed+permuted
  unsigned short* Yb  = xb;                        // alias: xb dead after GEMM1

  constexpr int CVT_BLOCKS = (M * C + 3 * C * C + C * C) / 1024;  // 8192
  cvt_all<<<dim3(CVT_BLOCKS), 256, 0, stream>>>(x, w_attn, w_proj, xb);

  gemm_bt<1><<<dim3(3 * C / 128, M / 128), 512, 0, stream>>>(
      xb, wab, b_attn, 3 * C, C, Qb, Kb, Vb, nullptr);

  attn<<<dim3(BH, 8), 512, 0, stream>>>(Qb, Kb, Vb, Yb);

  gemm_bt<0><<<dim3(C / 128, M / 128), 512, 0, stream>>>(
      Yb, wpb, b_proj, C, C, nullptr, nullptr, nullptr, out);
}

// Round 20
// 102.753 us; speedup vs baseline: 1.1329x; 1.0271x over previous
//
#include <hip/hip_runtime.h>
#include <hip/hip_bf16.h>

typedef __attribute__((ext_vector_type(4))) float f32x4;
typedef __attribute__((ext_vector_type(8))) short bh8;

#define DEVI static __device__ __forceinline__

constexpr int Bn = 2, T = 2048, C = 1024, H = 16, HD = 64;
constexpr int BH = Bn * H;   // 32
constexpr int M  = Bn * T;   // 4096
// fold 1/sqrt(HD) and log2(e) into Q so softmax uses exp2
constexpr float QSC = 0.125f * 1.44269504088896f;

DEVI unsigned short f2bf(float f) {
  unsigned int u = __builtin_bit_cast(unsigned int, f);
  u += 0x7FFFu + ((u >> 16) & 1u);   // RTNE
  return (unsigned short)(u >> 16);
}

DEVI unsigned int cvtpk(float lo, float hi) {  // 2xf32 -> packed 2xbf16 (1 VALU op)
  unsigned int r;
  asm("v_cvt_pk_bf16_f32 %0, %1, %2" : "=v"(r) : "v"(lo), "v"(hi));
  return r;
}

DEVI float fexp2(float x) {  // raw v_exp_f32 (2^x); CDNA has HW interlocks
  float r;
  asm("v_exp_f32 %0, %1" : "=v"(r) : "v"(x));
  return r;
}

DEVI void gload16(const void* g, void* l) {
  __builtin_amdgcn_global_load_lds((const __attribute__((address_space(1))) void*)g,
                                   (__attribute__((address_space(3))) void*)l,
                                   16, 0, 0);
}

// one fused fp32->bf16 convert for x | w_attn | w_proj (outputs contiguous in ws)
__global__ __launch_bounds__(256) void cvt_all(const float* __restrict__ x,
                                               const float* __restrict__ wa,
                                               const float* __restrict__ wp,
                                               unsigned short* __restrict__ out) {
  constexpr size_t n0 = (size_t)M * C;            // x
  constexpr size_t n1 = n0 + (size_t)3 * C * C;   // + w_attn
  const size_t i = ((size_t)blockIdx.x * 256 + threadIdx.x) * 4;
  const float* src;
  size_t off;
  if (i < n0)      { src = x;  off = i; }
  else if (i < n1) { src = wa; off = i - n0; }
  else             { src = wp; off = i - n1; }
  const float4 v = *(const float4*)(src + off);
  ushort4 o;
  o.x = f2bf(v.x); o.y = f2bf(v.y); o.z = f2bf(v.z); o.w = f2bf(v.w);
  *(ushort4*)(out + i) = o;
}

// C = A @ B^T (+bias). 128x128 tile, BK=64, 16x16x32 bf16 MFMA.
// R19-proven: R5 memory structure (single-buffered, same staging/swizzle/
// barriers/grid) with 8 WAVES per block (wave = 32x64 sub-tile, acc[2][4]):
// waves/CU at 3 blocks/CU = 24, doubling the m114 cross-block overlap pool.
// EPI 0: fp32 out + bias. EPI 1: qkv scatter; V kv-PERMUTED (see attn).
template <int EPI>
__global__ __launch_bounds__(512, 6) void gemm_bt(
    const unsigned short* __restrict__ A, const unsigned short* __restrict__ Bw,
    const float* __restrict__ bias, int N, int K,
    unsigned short* __restrict__ Qb, unsigned short* __restrict__ Kb,
    unsigned short* __restrict__ Vb, float* __restrict__ Outf) {
  __shared__ unsigned short As[128 * 64];
  __shared__ unsigned short Bs[128 * 64];

  const int tid  = threadIdx.x;
  const int lane = tid & 63;
  const int wid  = tid >> 6;          // 0..7
  const int wm = wid >> 1, wn = wid & 1;  // 4x2 wave grid: 32-row x 64-col
  const int m0 = blockIdx.y * 128;
  const int n0 = blockIdx.x * 128;
  const int l15 = lane & 15, l4 = lane >> 4;

  const int srow = lane >> 3;
  const int gp   = lane & 7;

  const unsigned short* Ab = A + (size_t)m0 * K;
  const unsigned short* Bb = Bw + (size_t)n0 * K;

  f32x4 acc[2][4] = {};

  for (int kt = 0; kt < K; kt += 64) {
    __syncthreads();
#pragma unroll
    for (int sl = 0; sl < 2; ++sl) {     // 8 waves x 2 slabs x 8 rows = 128 rows
      const int row = wid * 16 + sl * 8 + srow;
      const int gs  = gp ^ (row & 7);
      gload16(Ab + (size_t)row * K + kt + gs * 8, &As[(wid * 16 + sl * 8) * 64]);
      gload16(Bb + (size_t)row * K + kt + gs * 8, &Bs[(wid * 16 + sl * 8) * 64]);
    }
    __syncthreads();

#pragma unroll
    for (int kk = 0; kk < 2; ++kk) {
      bh8 af[2], bfr[4];
#pragma unroll
      for (int i = 0; i < 2; ++i) {
        const int row  = wm * 32 + i * 16 + l15;
        const int gran = kk * 4 + l4;
        af[i] = *(const bh8*)&As[row * 64 + ((gran ^ (row & 7)) * 8)];
      }
#pragma unroll
      for (int j = 0; j < 4; ++j) {
        const int row  = wn * 64 + j * 16 + l15;
        const int gran = kk * 4 + l4;
        bfr[j] = *(const bh8*)&Bs[row * 64 + ((gran ^ (row & 7)) * 8)];
      }
#pragma unroll
      for (int i = 0; i < 2; ++i)
#pragma unroll
        for (int j = 0; j < 4; ++j)
          acc[i][j] = __builtin_amdgcn_mfma_f32_16x16x32_bf16(af[i], bfr[j],
                                                              acc[i][j], 0, 0, 0);
    }
  }

  const int rbase = m0 + wm * 32 + (l4 << 2);
  const int cbase = n0 + wn * 64 + l15;

  if (EPI == 0) {
#pragma unroll
    for (int j = 0; j < 4; ++j) {
      const int n = cbase + j * 16;
      const float bv = bias[n];
#pragma unroll
      for (int i = 0; i < 2; ++i)
#pragma unroll
        for (int r = 0; r < 4; ++r) {
          const int m = rbase + i * 16 + r;
          Outf[(size_t)m * N + n] = acc[i][j][r] + bv;
        }
    }
  } else {
#pragma unroll
    for (int j = 0; j < 4; ++j) {
      const int n = cbase + j * 16;
      const float bv = bias[n];
      const int part = n >> 10;      // 0:q 1:k 2:v
      const int nn = n & 1023;
      const int h = nn >> 6, d = nn & 63;
#pragma unroll
      for (int i = 0; i < 2; ++i)
#pragma unroll
        for (int r = 0; r < 4; ++r) {
          const int m = rbase + i * 16 + r;
          const int b = m >> 11, t = m & (T - 1);
          const int bh = b * H + h;
          const float val = acc[i][j][r] + bv;
          if (part == 0)
            Qb[((size_t)(bh * T + t)) * HD + d] = f2bf(val * QSC);
          else if (part == 1)
            Kb[((size_t)(bh * T + t)) * HD + d] = f2bf(val);
          else {
            // kv-permutation (bits 0..4 only -> valid for any KVBLK>=32):
            // kp=[..|b1|l4|r] -> kap=[..|l4|b1|r]
            const int kp  = t & 127;
            const int kap = (kp & ~31) | (((kp >> 2) & 3) << 3) |
                            (((kp >> 4) & 1) << 2) | (kp & 3);
            const int tp  = (t & ~127) | kap;
            Vb[((size_t)(bh * HD + d)) * T + tp] = f2bf(val);  // transposed+permuted
          }
        }
    }
  }
}

// ---------------------------------------------------------------------------
// Flash attention, causal. Grid: (BH=32, 8). Block: 1024 thr = 16 waves.
// R20: the R19 transform applied to attn — SAME memory structure as the
// 4x-verified R13 attn (KVBLK=64, same K/V LDS layout + XOR(row&7) swizzle,
// same prefetch/drain cadence, 17 lockstep iters) but 16 waves: 2 kv-parity
// groups x 8 waves x 16 q-rows (was 2x4x32). Per-wave serial softmax halves
// (16 exp2 vs 32) while waves/SIMD doubles 2->4 — constant total work,
// double the TLP pool hiding the ds_read->MFMA->softmax chain. Avoids R14's
// traps: per-iter fixed costs unchanged (KVBLK still 64), V rows stay 128B
// so the swizzle stays conflict-free. Merge scratch Mg[8][64][19].
// Swapped QK^T, in-register P via cvtpk (V kv-permuted at GEMM1), defer-max.
// ---------------------------------------------------------------------------
__global__ __launch_bounds__(1024, 4) void attn(
    const unsigned short* __restrict__ Qb, const unsigned short* __restrict__ Kb,
    const unsigned short* __restrict__ Vb, unsigned short* __restrict__ Yb) {
  __shared__ unsigned short Ks[2][2][64 * 64];   // [group][dbuf]
  __shared__ unsigned short Vs[2][2][64 * 64];
  __shared__ float Mg[8][64][19];                // merge scratch (odd pad)

  const int tid  = threadIdx.x;
  const int lane = tid & 63;
  const int wid  = tid >> 6;          // 0..15
  const int g    = wid >> 3;          // kv-parity group
  const int wv   = wid & 7;           // wave within group (0..7)
  const int bh   = blockIdx.x;
  const int b = bh >> 4, h = bh & 15;
  const int qa = blockIdx.y;          // 0..7 ; paired tile = 15-qa
  const int p0n = qa + 1;             // local iters in pass 0 (per group); total 17

  const int l4  = lane >> 4;          // 0..3
  const int l15 = lane & 15;

  const unsigned short* Kbh = Kb + (size_t)bh * T * HD;
  const unsigned short* Vbh = Vb + (size_t)bh * HD * T;

  const int sr = lane >> 3, sg = lane & 7;

  // Q fragment (B-operand), 16 q-rows/wave, 2 kk (identical for both groups)
  bh8 qk[2];
  auto loadQ = [&](int tile) {
    const size_t qo =
        ((size_t)(bh * T + tile * 128 + wv * 16 + l15)) * HD + l4 * 8;
    qk[0] = *(const bh8*)&Qb[qo];
    qk[1] = *(const bh8*)&Qb[qo + 32];
  };
  loadQ(qa);

  f32x4 o[4] = {};
  float mcur = -1e30f, lsum = 0.f;

  // staging: group's 8 waves each stage 8 K rows + 8 V rows (one slab each)
  auto stage = [&](int buf, int kt) {
    const int row = wv * 8 + sr;
    const int gs  = sg ^ (row & 7);
    gload16(Kbh + (size_t)(kt + row) * HD + gs * 8, &Ks[g][buf][(wv * 8) * 64]);
    gload16(Vbh + (size_t)row * T + kt + gs * 8,    &Vs[g][buf][(wv * 8) * 64]);
  };

  // merge the two groups' partials for tile qt; group0 writes Yb
  auto flush = [&](int qt) {
    __syncthreads();
    if (g == 1) {
#pragma unroll
      for (int dj = 0; dj < 4; ++dj)
#pragma unroll
        for (int r = 0; r < 4; ++r)
          Mg[wv][lane][dj * 4 + r] = o[dj][r];
      Mg[wv][lane][16] = mcur;
      Mg[wv][lane][17] = lsum;
    }
    __syncthreads();
    if (g == 0) {
      const float mb = Mg[wv][lane][16];
      const float lb = Mg[wv][lane][17];
      const float m  = fmaxf(mcur, mb);
      const float wa = fexp2(mcur - m);
      const float wb = fexp2(mb - m);
      const float inv = 1.f / (lsum * wa + lb * wb);
      const int t = qt * 128 + wv * 16 + l15;
#pragma unroll
      for (int dj = 0; dj < 4; ++dj) {
        const float* mo = &Mg[wv][lane][dj * 4];
        ushort4 hw;
        hw.x = f2bf((o[dj][0] * wa + mo[0] * wb) * inv);
        hw.y = f2bf((o[dj][1] * wa + mo[1] * wb) * inv);
        hw.z = f2bf((o[dj][2] * wa + mo[2] * wb) * inv);
        hw.w = f2bf((o[dj][3] * wa + mo[3] * wb) * inv);
        *(ushort4*)&Yb[((size_t)(b * T + t)) * C + h * HD + dj * 16 + l4 * 4] = hw;
      }
    }
    __syncthreads();
  };

  // prologue: stage this group's unit 0 (kv parity g) into buffer 0
  stage(0, g * 64);
  __syncthreads();

  int cur = 0;
  for (int i = 0; i < 17; ++i) {
    // ---- pass boundary: merge+flush tile qa, reset, switch Q ----
    if (i == p0n) {
      flush(qa);
      mcur = -1e30f; lsum = 0.f;
#pragma unroll
      for (int dj = 0; dj < 4; ++dj) o[dj] = f32x4{0.f, 0.f, 0.f, 0.f};
      loadQ(15 - qa);
    }

    // ---- prefetch this group's next unit ----
    if (i < 16) {
      const int ni  = i + 1;
      const int nli = (ni >= p0n) ? ni - p0n : ni;
      stage(cur ^ 1, (2 * nli + g) * 64);
    }

    const int li = (i >= p0n) ? i - p0n : i;
    const int qt = (i >= p0n) ? 15 - qa : qa;
    const int kt = (2 * li + g) * 64;   // absolute kv offset of this unit

    // ---- S^T = K Q^T : s[j][r] = S[kv=kt+j*16+l4*4+r][q=..+wv*16+l15] ----
    f32x4 s[4] = {};
#pragma unroll
    for (int kk = 0; kk < 2; ++kk) {
      __builtin_amdgcn_s_setprio(1);
#pragma unroll
      for (int j = 0; j < 4; ++j) {
        const int row  = j * 16 + l15;
        const int gran = kk * 4 + l4;
        const bh8 kfr = *(const bh8*)&Ks[g][cur][row * 64 + ((gran ^ (row & 7)) * 8)];
        s[j] = __builtin_amdgcn_mfma_f32_16x16x32_bf16(kfr, qk[kk], s[j], 0, 0, 0);
      }
      __builtin_amdgcn_s_setprio(0);
    }

    // ---- causal mask (diag-touching units only) ----
    if (kt >= qt * 128) {
      const int kbase = kt - qt * 128;
      const int qloc  = wv * 16 + l15;
#pragma unroll
      for (int j = 0; j < 4; ++j)
#pragma unroll
        for (int r = 0; r < 4; ++r) {
          const int kvl = kbase + j * 16 + l4 * 4 + r;
          if (kvl > qloc) s[j][r] = -1e30f;
        }
    }

    // ---- online softmax: per-lane row, 2 shuffles per reduce ----
    float mx = fmaxf(fmaxf(s[0][0], s[0][1]), fmaxf(s[0][2], s[0][3]));
#pragma unroll
    for (int j = 1; j < 4; ++j)
      mx = fmaxf(mx, fmaxf(fmaxf(s[j][0], s[j][1]), fmaxf(s[j][2], s[j][3])));
    mx = fmaxf(mx, __shfl_xor(mx, 16));
    mx = fmaxf(mx, __shfl_xor(mx, 32));
    if (__any(mx > mcur + 8.f)) {          // defer-max (T13)
      const float mnew  = fmaxf(mcur, mx);
      const float alpha = fexp2(mcur - mnew);
      mcur = mnew; lsum *= alpha;
#pragma unroll
      for (int dj = 0; dj < 4; ++dj) o[dj] *= alpha;
    }
    float ps = 0.f;
#pragma unroll
    for (int j = 0; j < 4; ++j)
#pragma unroll
      for (int r = 0; r < 4; ++r) {
        const float p = fexp2(s[j][r] - mcur);
        s[j][r] = p;
        ps += p;
      }
    ps += __shfl_xor(ps, 16);
    ps += __shfl_xor(ps, 32);
    lsum += ps;

    // ---- O^T += V^T P : P packed in-register (V kv-permuted at GEMM1) ----
#pragma unroll
    for (int kk2 = 0; kk2 < 2; ++kk2) {
      const int gran = kk2 * 4 + l4;
      int4 pw;
      pw.x = cvtpk(s[2 * kk2][0], s[2 * kk2][1]);
      pw.y = cvtpk(s[2 * kk2][2], s[2 * kk2][3]);
      pw.z = cvtpk(s[2 * kk2 + 1][0], s[2 * kk2 + 1][1]);
      pw.w = cvtpk(s[2 * kk2 + 1][2], s[2 * kk2 + 1][3]);
      const bh8 pf = __builtin_bit_cast(bh8, pw);
      __builtin_amdgcn_s_setprio(1);
#pragma unroll
      for (int dj = 0; dj < 4; ++dj) {
        const int row = dj * 16 + l15;
        const bh8 vf = *(const bh8*)&Vs[g][cur][row * 64 + ((gran ^ (row & 7)) * 8)];
        o[dj] = __builtin_amdgcn_mfma_f32_16x16x32_bf16(vf, pf, o[dj], 0, 0, 0);
      }
      __builtin_amdgcn_s_setprio(0);
    }

    __syncthreads();   // drains vmcnt(0): prefetched unit ready; buffer reuse safe
    cur ^= 1;
  }

  // ---- merge+flush pass-1 tile ----
  flush(15 - qa);
}

extern "C" void kernel_launch(void* const* d_in, const int* in_sizes, int n_in,
                              void* d_out, int out_size, void* d_ws, size_t ws_size,
                              hipStream_t stream) {
  const float* x      = (const float*)d_in[0];
  const float* w_attn = (const float*)d_in[1];
  const float* b_attn = (const float*)d_in[2];
  const float* w_proj = (const float*)d_in[3];
  const float* b_proj = (const float*)d_in[4];
  float* out = (float*)d_out;

  unsigned short* xb  = (unsigned short*)d_ws;
  unsigned short* wab = xb  + (size_t)M * C;       // w_attn bf16 [3C][C]
  unsigned short* wpb = wab + (size_t)3 * C * C;   // w_proj bf16 [C][C]
  unsigned short* Qb  = wpb + (size_t)C * C;       // [BH][T][HD] (pre-scaled)
  unsigned short* Kb  = Qb  + (size_t)M * C;       // [BH][T][HD]
  unsigned short* Vb  = Kb  + (size_t)M * C;       // [BH][HD][T] transposed+permuted
  unsigned short* Yb  = xb;                        // alias: xb dead after GEMM1

  constexpr int CVT_BLOCKS = (M * C + 3 * C * C + C * C) / 1024;  // 8192
  cvt_all<<<dim3(CVT_BLOCKS), 256, 0, stream>>>(x, w_attn, w_proj, xb);

  gemm_bt<1><<<dim3(3 * C / 128, M / 128), 512, 0, stream>>>(
      xb, wab, b_attn, 3 * C, C, Qb, Kb, Vb, nullptr);

  attn<<<dim3(BH, 8), 1024, 0, stream>>>(Qb, Kb, Vb, Yb);

  gemm_bt<0><<<dim3(C / 128, M / 128), 512, 0, stream>>>(
      Yb, wpb, b_proj, C, C, nullptr, nullptr, nullptr, out);
}